// Round 6
// baseline (711.939 us; speedup 1.0000x reference)
//
#include <hip/hip_runtime.h>
#include <math.h>

#define E_    3
#define QE_   60000
#define QTOT  180000      // E_*QE_
#define P_    40
#define H_    20
#define NIMG_ 1800
#define NNZ_  14400000
#define BLK   256
#define NB    704         // ceil(QTOT/BLK)

// column-window partition for the sparse force accumulation
#define CW_BITS 12
#define CW      4096                  // cols per window (16 KB LDS accumulator)
#define NBIN    132                   // ceil(3*QTOT / CW)
#define SUBS    8                     // sub-slices per bin in force kernel
#define SC      8192                  // nnz items per chunk
#define NSB     1758                  // ceil(NNZ_/SC)  (input chunking)

// row-slice partition (v3): 131072 dE rows = 512 KB per slice -> fits XCD L2
#define SLICE_SHIFT 17
#define NSLICE  55                    // ceil(7.2M / 131072)
#define MAXCH   1813                  // max chunks after slicing (NSB + NSLICE)
#define FS_GRID 768                   // fscatter3 blocks (3/CU)
#define FS_PERX 96                    // blocks per XCD group

// ctrl block int offsets (within ctrl region)
#define C_CNT   0      // [55]  slice counts
#define C_SBASE 64     // [56]  slice base (aligned4)
#define C_SCUR  128    // [55]  slice write cursors
#define C_TOT   184    // [1]   total chunks
#define C_CHS   192    // [1813] chunk -> slice
#define C_CHST  2048   // [1813] chunk -> start pos
#define C_CHLEN 4096   // [1813] chunk -> length
#define C_GRP   6144   // [8*256] per-XCD-group chunk list
#define C_GCNT  8192   // [8]   group counts
#define C_INTS  8448

typedef int   vi4 __attribute__((ext_vector_type(4)));
typedef float vf4 __attribute__((ext_vector_type(4)));
typedef unsigned uint32;

// ---------------- zero init -------------------------------------------------
__global__ void zero_kernel(float* __restrict__ out, int n) {
    int i = blockIdx.x * blockDim.x + threadIdx.x;
    if (i < n) out[i] = 0.0f;
}
__global__ void zero_ctrl_kernel(int* __restrict__ ctrl) {
    ctrl[threadIdx.x] = 0;   // zeros C_CNT (+ slack), 256 ints
}

// ---------------- stable counting sort for atom ranks ----------------------
__global__ void hist_kernel(const int* __restrict__ img, int* __restrict__ g_hist) {
    __shared__ int h[NIMG_];
    const int t = threadIdx.x, b = blockIdx.x;
    for (int v = t; v < NIMG_; v += BLK) h[v] = 0;
    __syncthreads();
    int a = b * BLK + t;
    if (a < QTOT) atomicAdd(&h[img[a]], 1);
    __syncthreads();
    for (int v = t; v < NIMG_; v += BLK) g_hist[v * NB + b] = h[v];
}

__global__ void scan_blocks_kernel(int* __restrict__ g_hist, int* __restrict__ g_total) {
    __shared__ int s[BLK];
    const int v = blockIdx.x, t = threadIdx.x;
    int carry = 0;
    for (int c = 0; c < NB; c += BLK) {
        int idx = c + t;
        int val = (idx < NB) ? g_hist[v * NB + idx] : 0;
        s[t] = val; __syncthreads();
        for (int off = 1; off < BLK; off <<= 1) {
            int tmp = (t >= off) ? s[t - off] : 0;
            __syncthreads();
            s[t] += tmp;
            __syncthreads();
        }
        int excl = s[t] - val;
        int tot  = s[BLK - 1];
        if (idx < NB) g_hist[v * NB + idx] = carry + excl;
        carry += tot;
        __syncthreads();
    }
    if (t == 0) g_total[v] = carry;
}

__global__ void scan_buckets_kernel(const int* __restrict__ g_total, int* __restrict__ g_base) {
    __shared__ int s[BLK];
    const int t = threadIdx.x;
    int carry = 0;
    for (int c = 0; c < NIMG_; c += BLK) {
        int idx = c + t;
        int val = (idx < NIMG_) ? g_total[idx] : 0;
        s[t] = val; __syncthreads();
        for (int off = 1; off < BLK; off <<= 1) {
            int tmp = (t >= off) ? s[t - off] : 0;
            __syncthreads();
            s[t] += tmp;
            __syncthreads();
        }
        if (idx < NIMG_) g_base[idx] = carry + (s[t] - val);
        carry += s[BLK - 1];
        __syncthreads();
    }
}

__global__ void rank_kernel(const int* __restrict__ img, const int* __restrict__ g_hist,
                            const int* __restrict__ g_base, int* __restrict__ rank) {
    __shared__ int simg[BLK];
    const int t = threadIdx.x, b = blockIdx.x;
    int a = b * BLK + t;
    int v = (a < QTOT) ? img[a] : -1;
    simg[t] = v;
    __syncthreads();
    if (a < QTOT) {
        int local = 0;
        for (int j = 0; j < t; ++j) {
            if (simg[j] == v) local++;
        }
        rank[a] = g_base[v] + g_hist[v * NB + b] + local;
    }
}

// ---------------- per-atom MLP forward + backward ---------------------------
__global__ __launch_bounds__(BLK) void mlp_kernel(
    const float* __restrict__ fps, const float* __restrict__ W1, const float* __restrict__ b1,
    const float* __restrict__ W2, const float* __restrict__ b2, const float* __restrict__ W3,
    const float* __restrict__ b3, const int* __restrict__ img, const int* __restrict__ rank,
    float* __restrict__ energy, float* __restrict__ dEflat)
{
    __shared__ float sW1[P_ * H_], sW2[H_ * H_], sW3[H_], sB1[H_], sB2[H_];
    __shared__ float sB3;
    const int e = blockIdx.y;
    const int t = threadIdx.x;
    for (int i = t; i < P_ * H_; i += BLK) sW1[i] = W1[e * P_ * H_ + i];
    for (int i = t; i < H_ * H_; i += BLK) sW2[i] = W2[e * H_ * H_ + i];
    if (t < H_) { sW3[t] = W3[e * H_ + t]; sB1[t] = b1[e * H_ + t]; sB2[t] = b2[e * H_ + t]; }
    if (t == 0) sB3 = b3[e];
    __syncthreads();

    int q = blockIdx.x * BLK + t;
    if (q >= QE_) return;
    int a = e * QE_ + q;

    const vf4* xp = (const vf4*)(fps + (size_t)a * P_);
    float x[P_];
    #pragma unroll
    for (int p = 0; p < P_; p += 4) {
        vf4 v4 = __builtin_nontemporal_load(xp + (p >> 2));
        x[p] = v4.x; x[p+1] = v4.y; x[p+2] = v4.z; x[p+3] = v4.w;
    }

    float h1v[H_], h2v[H_];
    #pragma unroll
    for (int i = 0; i < H_; ++i) {
        float z = sB1[i];
        #pragma unroll
        for (int p = 0; p < P_; ++p) z += x[p] * sW1[p * H_ + i];
        h1v[i] = tanhf(z);
    }
    #pragma unroll
    for (int i = 0; i < H_; ++i) {
        float z = sB2[i];
        #pragma unroll
        for (int j = 0; j < H_; ++j) z += h1v[j] * sW2[j * H_ + i];
        h2v[i] = tanhf(z);
    }
    float ea = sB3;
    #pragma unroll
    for (int i = 0; i < H_; ++i) ea += h2v[i] * sW3[i];
    atomicAdd(&energy[img[a]], ea);

    float dz2[H_];
    #pragma unroll
    for (int i = 0; i < H_; ++i) dz2[i] = sW3[i] * (1.0f - h2v[i] * h2v[i]);
    float dz1[H_];
    #pragma unroll
    for (int i = 0; i < H_; ++i) {
        float d = 0.0f;
        #pragma unroll
        for (int j = 0; j < H_; ++j) d += sW2[i * H_ + j] * dz2[j];
        dz1[i] = d * (1.0f - h1v[i] * h1v[i]);
    }
    float* op = dEflat + (size_t)rank[a] * P_;
    #pragma unroll
    for (int p = 0; p < P_; p += 4) {
        float4 v4;
        float d0 = 0.f, d1 = 0.f, d2 = 0.f, d3 = 0.f;
        #pragma unroll
        for (int i = 0; i < H_; ++i) {
            d0 += sW1[(p    ) * H_ + i] * dz1[i];
            d1 += sW1[(p + 1) * H_ + i] * dz1[i];
            d2 += sW1[(p + 2) * H_ + i] * dz1[i];
            d3 += sW1[(p + 3) * H_ + i] * dz1[i];
        }
        v4.x = d0; v4.y = d1; v4.z = d2; v4.w = d3;
        *(float4*)(op + p) = v4;   // cacheable: re-read by fscatter gather
    }
}

// ================= v3: row-slice sort + XCD-pinned gather ===================

// S0: global slice histogram of rows
__global__ __launch_bounds__(BLK) void slice_hist_kernel(const int* __restrict__ rows,
                                                         int* __restrict__ ctrl) {
    __shared__ int h[NSLICE];
    const int t = threadIdx.x, b = blockIdx.x;
    if (t < NSLICE) h[t] = 0;
    __syncthreads();
    const int base = b * SC;
    if (base + SC <= NNZ_) {
        const vi4* r4 = (const vi4*)(rows + base);
        #pragma unroll
        for (int j = 0; j < SC / (BLK * 4); ++j) {
            vi4 rr = __builtin_nontemporal_load(r4 + j * BLK + t);
            atomicAdd(&h[rr.x >> SLICE_SHIFT], 1);
            atomicAdd(&h[rr.y >> SLICE_SHIFT], 1);
            atomicAdd(&h[rr.z >> SLICE_SHIFT], 1);
            atomicAdd(&h[rr.w >> SLICE_SHIFT], 1);
        }
    } else {
        for (int j = 0; j < SC / BLK; ++j) {
            int k = base + j * BLK + t;
            if (k < NNZ_) atomicAdd(&h[rows[k] >> SLICE_SHIFT], 1);
        }
    }
    __syncthreads();
    if (t < NSLICE && h[t] > 0) atomicAdd(&ctrl[C_CNT + t], h[t]);
}

// S0b: build slice bases, cursors, chunk tables, per-XCD-group chunk lists.
__global__ void plan_kernel(int* __restrict__ ctrl) {
    __shared__ int scnt[NSLICE], sb[NSLICE + 1], cb[NSLICE + 1], gp[NSLICE];
    __shared__ int g8[8], tot_s;
    const int t = threadIdx.x;
    if (t < NSLICE) scnt[t] = ctrl[C_CNT + t];
    __syncthreads();
    if (t == 0) {
        int run = 0, crun = 0;
        int gs[8]; for (int x = 0; x < 8; ++x) gs[x] = 0;
        for (int s = 0; s < NSLICE; ++s) {
            sb[s] = run;
            run += scnt[s];
            run = (run + 3) & ~3;                 // 16-B align next slice base
            int nc = (scnt[s] + SC - 1) / SC;
            cb[s] = crun; crun += nc;
            int x = s & 7;
            gp[s] = gs[x]; gs[x] += nc;
        }
        sb[NSLICE] = run; cb[NSLICE] = crun; tot_s = crun;
        for (int x = 0; x < 8; ++x) g8[x] = gs[x];
    }
    __syncthreads();
    const int tot = tot_s;
    if (t < NSLICE) { ctrl[C_SBASE + t] = sb[t]; ctrl[C_SCUR + t] = sb[t]; }
    if (t == 0) { ctrl[C_SBASE + NSLICE] = sb[NSLICE]; ctrl[C_TOT] = tot; }
    if (t < 8) ctrl[C_GCNT + t] = g8[t];
    for (int idx = t; idx < MAXCH; idx += BLK) {
        if (idx < tot) {
            int s = 0;
            for (int k = 0; k < NSLICE; ++k) if (cb[k] <= idx) s = k;   // LDS scan
            int c = idx - cb[s];
            ctrl[C_CHS + idx]   = s;
            ctrl[C_CHST + idx]  = sb[s] + c * SC;
            ctrl[C_CHLEN + idx] = min(SC, scnt[s] - c * SC);
            ctrl[C_GRP + (s & 7) * 256 + gp[s] + c] = idx;
        } else {
            ctrl[C_CHS + idx] = 0; ctrl[C_CHST + idx] = 0; ctrl[C_CHLEN + idx] = 0;
        }
    }
}

// S1: counting sort into slice order; emit packed items.
// itemX = (val15 << 17) | rowLocal17   (val15 = round-to-nearest top 15 bits)
// itemY = col
__global__ __launch_bounds__(BLK) void slice_sort_kernel(
    const int* __restrict__ rows, const int* __restrict__ cols, const float* __restrict__ vals,
    int* __restrict__ ctrl, uint32* __restrict__ itemX, uint32* __restrict__ itemY)
{
    __shared__ uint32 rbuf[SC];      // 32 KB (rows -> vals -> cols)
    __shared__ uint32 sbuf[SC];      // 32 KB ((localIdx:13 | rowLocal:17) sorted)
    __shared__ int h[NSLICE], lb[NSLICE + 1], res[NSLICE], cur[NSLICE];
    const int t = threadIdx.x, b = blockIdx.x;
    const int base = b * SC;
    const int len = min(SC, NNZ_ - base);
    const bool full = (len == SC);

    if (t < NSLICE) h[t] = 0;
    __syncthreads();
    if (full) {
        const vi4* r4 = (const vi4*)(rows + base);
        #pragma unroll
        for (int j = 0; j < SC / (BLK * 4); ++j) {
            int idx = j * BLK + t;
            vi4 rr = __builtin_nontemporal_load(r4 + idx);
            rbuf[idx * 4 + 0] = (uint32)rr.x; atomicAdd(&h[rr.x >> SLICE_SHIFT], 1);
            rbuf[idx * 4 + 1] = (uint32)rr.y; atomicAdd(&h[rr.y >> SLICE_SHIFT], 1);
            rbuf[idx * 4 + 2] = (uint32)rr.z; atomicAdd(&h[rr.z >> SLICE_SHIFT], 1);
            rbuf[idx * 4 + 3] = (uint32)rr.w; atomicAdd(&h[rr.w >> SLICE_SHIFT], 1);
        }
    } else {
        for (int j = t; j < len; j += BLK) {
            int r = rows[base + j];
            rbuf[j] = (uint32)r;
            atomicAdd(&h[r >> SLICE_SHIFT], 1);
        }
    }
    __syncthreads();
    if (t == 0) {
        int run = 0;
        for (int s = 0; s < NSLICE; ++s) { lb[s] = run; run += h[s]; }
        lb[NSLICE] = run;
    }
    __syncthreads();
    if (t < NSLICE) {
        cur[t] = lb[t];
        res[t] = (h[t] > 0) ? atomicAdd(&ctrl[C_SCUR + t], h[t]) : 0;
    }
    __syncthreads();
    // place (localIdx | rowLocal) into sorted slot
    for (int j = t; j < len; j += BLK) {
        uint32 r = rbuf[j];
        int bn = (int)(r >> SLICE_SHIFT);
        int pos = atomicAdd(&cur[bn], 1);
        sbuf[pos] = ((uint32)j << SLICE_SHIFT) | (r & 0x1FFFFu);
    }
    __syncthreads();
    // load vals over rbuf
    if (full) {
        const vi4* v4 = (const vi4*)(vals + base);
        #pragma unroll
        for (int j = 0; j < SC / (BLK * 4); ++j) {
            int idx = j * BLK + t;
            vi4 vv = __builtin_nontemporal_load(v4 + idx);
            rbuf[idx * 4 + 0] = (uint32)vv.x; rbuf[idx * 4 + 1] = (uint32)vv.y;
            rbuf[idx * 4 + 2] = (uint32)vv.z; rbuf[idx * 4 + 3] = (uint32)vv.w;
        }
    } else {
        for (int j = t; j < len; j += BLK) rbuf[j] = ((const uint32*)vals)[base + j];
    }
    __syncthreads();
    // write itemX in sorted order
    for (int j = t; j < len; j += BLK) {
        uint32 e = sbuf[j];
        int i = (int)(e >> SLICE_SHIFT);
        uint32 rl = e & 0x1FFFFu;
        uint32 v15 = (rbuf[i] + 0x10000u) >> 17;
        int lo = 0, hi = NSLICE;
        while (hi - lo > 1) { int mid = (lo + hi) >> 1; if (lb[mid] <= j) lo = mid; else hi = mid; }
        int dst = res[lo] + (j - lb[lo]);
        itemX[dst] = (v15 << 17) | rl;
    }
    __syncthreads();
    // load cols over rbuf
    if (full) {
        const vi4* c4 = (const vi4*)(cols + base);
        #pragma unroll
        for (int j = 0; j < SC / (BLK * 4); ++j) {
            int idx = j * BLK + t;
            vi4 cc = __builtin_nontemporal_load(c4 + idx);
            rbuf[idx * 4 + 0] = (uint32)cc.x; rbuf[idx * 4 + 1] = (uint32)cc.y;
            rbuf[idx * 4 + 2] = (uint32)cc.z; rbuf[idx * 4 + 3] = (uint32)cc.w;
        }
    } else {
        for (int j = t; j < len; j += BLK) rbuf[j] = (uint32)cols[base + j];
    }
    __syncthreads();
    // write itemY in sorted order
    for (int j = t; j < len; j += BLK) {
        uint32 e = sbuf[j];
        int i = (int)(e >> SLICE_SHIFT);
        int lo = 0, hi = NSLICE;
        while (hi - lo > 1) { int mid = (lo + hi) >> 1; if (lb[mid] <= j) lo = mid; else hi = mid; }
        int dst = res[lo] + (j - lb[lo]);
        itemY[dst] = rbuf[i];
    }
}

// fhist3: per-chunk col-window histogram over slice-sorted items.
__global__ __launch_bounds__(BLK) void fhist3_kernel(const uint32* __restrict__ itemY,
                                                     const int* __restrict__ ctrl,
                                                     int* __restrict__ binHist) {
    __shared__ int h[NBIN];
    const int t = threadIdx.x, g = blockIdx.x;
    if (t < NBIN) h[t] = 0;
    __syncthreads();
    const int start = ctrl[C_CHST + g];
    const int len   = ctrl[C_CHLEN + g];
    if (len == SC) {
        const vi4* y4 = (const vi4*)(itemY + start);
        #pragma unroll
        for (int j = 0; j < SC / (BLK * 4); ++j) {
            vi4 yy = __builtin_nontemporal_load(y4 + j * BLK + t);
            atomicAdd(&h[yy.x >> CW_BITS], 1);
            atomicAdd(&h[yy.y >> CW_BITS], 1);
            atomicAdd(&h[yy.z >> CW_BITS], 1);
            atomicAdd(&h[yy.w >> CW_BITS], 1);
        }
    } else {
        for (int j = t; j < len; j += BLK)
            atomicAdd(&h[itemY[start + j] >> CW_BITS], 1);
    }
    __syncthreads();
    if (t < NBIN) binHist[t * MAXCH + g] = h[t];
}

// per-bin exclusive scan across n chunk slots (shared by v3 and fallback)
__global__ void fscan_blocks_kernel(int* __restrict__ binHist, int* __restrict__ binTotal,
                                    int n) {
    __shared__ int s[BLK];
    const int v = blockIdx.x, t = threadIdx.x;
    int carry = 0;
    for (int c = 0; c < n; c += BLK) {
        int idx = c + t;
        int val = (idx < n) ? binHist[v * n + idx] : 0;
        s[t] = val; __syncthreads();
        for (int off = 1; off < BLK; off <<= 1) {
            int tmp = (t >= off) ? s[t - off] : 0;
            __syncthreads();
            s[t] += tmp;
            __syncthreads();
        }
        int excl = s[t] - val;
        int tot  = s[BLK - 1];
        if (idx < n) binHist[v * n + idx] = carry + excl;
        carry += tot;
        __syncthreads();
    }
    if (t == 0) binTotal[v] = carry;
}

__global__ void fbase_kernel(const int* __restrict__ binTotal, int* __restrict__ binBase) {
    __shared__ int s[BLK];
    const int t = threadIdx.x;
    int v = (t < NBIN) ? binTotal[t] : 0;
    s[t] = v; __syncthreads();
    for (int off = 1; off < BLK; off <<= 1) {
        int tmp = (t >= off) ? s[t - off] : 0;
        __syncthreads();
        s[t] += tmp;
        __syncthreads();
    }
    if (t < NBIN) binBase[t] = s[t] - v;
    if (t == 0) binBase[NBIN] = s[BLK - 1];
}

// fscatter3: XCD-pinned chunks; gather dEflat (L2-resident slice), fused
// multiply, block-local col sort, coalesced write-out.
__global__ __launch_bounds__(BLK) void fscatter3_kernel(
    const uint32* __restrict__ itemX, const uint32* __restrict__ itemY,
    const float* __restrict__ dEflat, const int* __restrict__ ctrl,
    const int* __restrict__ binHist, const int* __restrict__ binBase,
    uint32* __restrict__ bm)
{
    __shared__ uint32 items[SC];          // 32 KB
    __shared__ unsigned char bns[SC];     //  8 KB
    __shared__ int h[NBIN], cur[NBIN], dlt[NBIN];
    __shared__ int sc[BLK];
    const int t = threadIdx.x;
    const int x = blockIdx.x & 7;         // assumed XCD (round-robin dispatch)
    const int r = blockIdx.x >> 3;
    const int gc = ctrl[C_GCNT + x];

    for (int w = r; w < gc; w += FS_PERX) {
        const int g     = ctrl[C_GRP + x * 256 + w];
        const int sl    = ctrl[C_CHS + g];
        const int start = ctrl[C_CHST + g];
        const int len   = ctrl[C_CHLEN + g];
        const int row0  = sl << SLICE_SHIFT;

        if (t < NBIN) h[t] = 0;
        __syncthreads();
        // local histogram over cols
        if (len == SC) {
            const vi4* y4 = (const vi4*)(itemY + start);
            #pragma unroll
            for (int j = 0; j < SC / (BLK * 4); ++j) {
                vi4 yy = __builtin_nontemporal_load(y4 + j * BLK + t);
                atomicAdd(&h[yy.x >> CW_BITS], 1);
                atomicAdd(&h[yy.y >> CW_BITS], 1);
                atomicAdd(&h[yy.z >> CW_BITS], 1);
                atomicAdd(&h[yy.w >> CW_BITS], 1);
            }
        } else {
            for (int j = t; j < len; j += BLK)
                atomicAdd(&h[itemY[start + j] >> CW_BITS], 1);
        }
        __syncthreads();
        // local scan -> cur/dlt
        {
            int v = (t < NBIN) ? h[t] : 0;
            sc[t] = v; __syncthreads();
            for (int off = 1; off < BLK; off <<= 1) {
                int tmp = (t >= off) ? sc[t - off] : 0;
                __syncthreads();
                sc[t] += tmp;
                __syncthreads();
            }
            if (t < NBIN) {
                int ls = sc[t] - v;
                cur[t] = ls;
                dlt[t] = binBase[t] + binHist[t * MAXCH + g] - ls;
            }
        }
        __syncthreads();
        // gather + fused multiply + local placement
        if (len == SC) {
            const vi4* x4 = (const vi4*)(itemX + start);
            const vi4* y4 = (const vi4*)(itemY + start);
            #pragma unroll 2
            for (int j = 0; j < SC / (BLK * 4); ++j) {
                int idx = j * BLK + t;
                vi4 xx = __builtin_nontemporal_load(x4 + idx);
                vi4 yy = __builtin_nontemporal_load(y4 + idx);
                float d0 = dEflat[row0 + (((uint32)xx.x) & 0x1FFFFu)];
                float d1 = dEflat[row0 + (((uint32)xx.y) & 0x1FFFFu)];
                float d2 = dEflat[row0 + (((uint32)xx.z) & 0x1FFFFu)];
                float d3 = dEflat[row0 + (((uint32)xx.w) & 0x1FFFFu)];
                #define PLACE3(XI, YI, DI)                                         \
                {                                                                  \
                    uint32 col = (uint32)(YI);                                     \
                    int bin = (int)(col >> CW_BITS);                               \
                    float val = __uint_as_float((((uint32)(XI)) >> 17) << 17);     \
                    uint32 u = __float_as_uint(-val * (DI));                       \
                    uint32 pk = ((col & (CW - 1)) << 20) | ((u + 0x800u) >> 12);   \
                    int pos = atomicAdd(&cur[bin], 1);                             \
                    items[pos] = pk;                                               \
                    bns[pos] = (unsigned char)bin;                                 \
                }
                PLACE3(xx.x, yy.x, d0)
                PLACE3(xx.y, yy.y, d1)
                PLACE3(xx.z, yy.z, d2)
                PLACE3(xx.w, yy.w, d3)
            }
        } else {
            for (int j = t; j < len; j += BLK) {
                uint32 xi = itemX[start + j];
                uint32 yi = itemY[start + j];
                float d = dEflat[row0 + (xi & 0x1FFFFu)];
                PLACE3(xi, yi, d)
            }
        }
        __syncthreads();
        // coalesced write-out in sorted order
        for (int i = t; i < len; i += BLK) {
            __builtin_nontemporal_store(items[i], &bm[dlt[bns[i]] + i]);
        }
        __syncthreads();
    }
}

// fforce: per (bin, sub-slice) LDS accumulation.
__global__ __launch_bounds__(BLK) void fforce_kernel(
    const uint32* __restrict__ bm, const int* __restrict__ binBase,
    float* __restrict__ partial)
{
    __shared__ float w[CW];
    const int t = threadIdx.x;
    const int bin = blockIdx.x >> 3;
    const int sub = blockIdx.x & (SUBS - 1);
    for (int i = t; i < CW; i += BLK) w[i] = 0.0f;
    __syncthreads();
    const int start = binBase[bin];
    const int cnt   = binBase[bin + 1] - start;
    const int sBeg  = start + (cnt * sub) / SUBS;
    const int sEnd  = start + (cnt * (sub + 1)) / SUBS;
    int i = sBeg + t;
    for (; i + 3 * BLK < sEnd; i += 4 * BLK) {
        uint32 p0 = __builtin_nontemporal_load(bm + i);
        uint32 p1 = __builtin_nontemporal_load(bm + i + BLK);
        uint32 p2 = __builtin_nontemporal_load(bm + i + 2 * BLK);
        uint32 p3 = __builtin_nontemporal_load(bm + i + 3 * BLK);
        atomicAdd(&w[p0 >> 20], __uint_as_float((p0 & 0xFFFFFu) << 12));
        atomicAdd(&w[p1 >> 20], __uint_as_float((p1 & 0xFFFFFu) << 12));
        atomicAdd(&w[p2 >> 20], __uint_as_float((p2 & 0xFFFFFu) << 12));
        atomicAdd(&w[p3 >> 20], __uint_as_float((p3 & 0xFFFFFu) << 12));
    }
    for (; i < sEnd; i += BLK) {
        uint32 p = bm[i];
        atomicAdd(&w[p >> 20], __uint_as_float((p & 0xFFFFFu) << 12));
    }
    __syncthreads();
    float* dst = partial + (size_t)blockIdx.x * CW;
    for (int k = t; k < CW; k += BLK) __builtin_nontemporal_store(w[k], dst + k);
}

__global__ void freduce_kernel(const float* __restrict__ partial, float* __restrict__ force) {
    int i = blockIdx.x * BLK + threadIdx.x;
    if (i < 3 * QTOT) {
        int bin = i >> CW_BITS, local = i & (CW - 1);
        const float* p = partial + (size_t)bin * (CW * SUBS) + local;
        float sum = 0.0f;
        #pragma unroll
        for (int k = 0; k < SUBS; ++k) sum += __builtin_nontemporal_load(p + k * CW);
        force[i] = sum;
    }
}

// ================= R5 fallback path (unsliced) ==============================
__global__ __launch_bounds__(BLK) void fhist_kernel(const int* __restrict__ cols,
                                                    int* __restrict__ binHist) {
    __shared__ int h[NBIN];
    const int t = threadIdx.x, b = blockIdx.x;
    if (t < NBIN) h[t] = 0;
    __syncthreads();
    const int base = b * SC;
    if (base + SC <= NNZ_) {
        const vi4* c4 = (const vi4*)(cols + base);
        #pragma unroll
        for (int j = 0; j < SC / (BLK * 4); ++j) {
            vi4 cc = __builtin_nontemporal_load(c4 + j * BLK + t);
            atomicAdd(&h[cc.x >> CW_BITS], 1);
            atomicAdd(&h[cc.y >> CW_BITS], 1);
            atomicAdd(&h[cc.z >> CW_BITS], 1);
            atomicAdd(&h[cc.w >> CW_BITS], 1);
        }
    } else {
        for (int j = 0; j < SC / BLK; ++j) {
            int k = base + j * BLK + t;
            if (k < NNZ_) atomicAdd(&h[cols[k] >> CW_BITS], 1);
        }
    }
    __syncthreads();
    if (t < NBIN) binHist[t * NSB + b] = h[t];
}

__global__ __launch_bounds__(BLK) void fscatter_kernel(
    const int* __restrict__ rows, const int* __restrict__ cols, const float* __restrict__ vals,
    const float* __restrict__ dEflat, const int* __restrict__ binHist,
    const int* __restrict__ binBase, uint32* __restrict__ bm)
{
    __shared__ uint32 items[SC];
    __shared__ unsigned char bins[SC];
    __shared__ int hist[NBIN];
    __shared__ int cursor[NBIN];
    __shared__ int delta[NBIN];
    __shared__ int s[BLK];
    const int t = threadIdx.x, b = blockIdx.x;
    const int base = b * SC;
    const int nIt = min(SC, NNZ_ - base);
    const bool full = (base + SC <= NNZ_);

    if (t < NBIN) hist[t] = 0;
    __syncthreads();
    if (full) {
        const vi4* c4 = (const vi4*)(cols + base);
        #pragma unroll
        for (int j = 0; j < SC / (BLK * 4); ++j) {
            vi4 cc = __builtin_nontemporal_load(c4 + j * BLK + t);
            atomicAdd(&hist[cc.x >> CW_BITS], 1);
            atomicAdd(&hist[cc.y >> CW_BITS], 1);
            atomicAdd(&hist[cc.z >> CW_BITS], 1);
            atomicAdd(&hist[cc.w >> CW_BITS], 1);
        }
    } else {
        for (int j = 0; j < SC / BLK; ++j) {
            int k = base + j * BLK + t;
            if (k < NNZ_) atomicAdd(&hist[cols[k] >> CW_BITS], 1);
        }
    }
    __syncthreads();
    {
        int v = (t < NBIN) ? hist[t] : 0;
        s[t] = v; __syncthreads();
        for (int off = 1; off < BLK; off <<= 1) {
            int tmp = (t >= off) ? s[t - off] : 0;
            __syncthreads();
            s[t] += tmp;
            __syncthreads();
        }
        if (t < NBIN) {
            int ls = s[t] - v;
            cursor[t] = ls;
            delta[t]  = binBase[t] + binHist[t * NSB + b] - ls;
        }
    }
    __syncthreads();
    if (full) {
        const vi4* c4 = (const vi4*)(cols + base);
        const vi4* r4 = (const vi4*)(rows + base);
        const vf4* v4 = (const vf4*)(vals + base);
        #pragma unroll 2
        for (int j = 0; j < SC / (BLK * 4); ++j) {
            int idx = j * BLK + t;
            vi4 cc = __builtin_nontemporal_load(c4 + idx);
            vi4 rr = __builtin_nontemporal_load(r4 + idx);
            vf4 vv = __builtin_nontemporal_load(v4 + idx);
            float d0 = dEflat[rr.x];
            float d1 = dEflat[rr.y];
            float d2 = dEflat[rr.z];
            float d3 = dEflat[rr.w];
            #define PLACE(CI, VI, DI)                                              \
            {                                                                      \
                int bin = (CI) >> CW_BITS;                                         \
                uint32 u = __float_as_uint(-(VI) * (DI));                          \
                uint32 pk = ((uint32)((CI) & (CW - 1)) << 20)                      \
                            | ((u + 0x800u) >> 12);                                \
                int pos = atomicAdd(&cursor[bin], 1);                              \
                items[pos] = pk;                                                   \
                bins[pos] = (unsigned char)bin;                                    \
            }
            PLACE(cc.x, vv.x, d0)
            PLACE(cc.y, vv.y, d1)
            PLACE(cc.z, vv.z, d2)
            PLACE(cc.w, vv.w, d3)
        }
    } else {
        for (int j = 0; j < SC / BLK; ++j) {
            int k = base + j * BLK + t;
            if (k < NNZ_) {
                int c = cols[k];
                float d = dEflat[rows[k]];
                float v = vals[k];
                PLACE(c, v, d)
            }
        }
    }
    __syncthreads();
    for (int i = t; i < nIt; i += BLK) {
        __builtin_nontemporal_store(items[i], &bm[delta[bins[i]] + i]);
    }
}

__global__ void force_kernel(const int* __restrict__ rows, const int* __restrict__ cols,
                             const float* __restrict__ vals, const float* __restrict__ dEflat,
                             float* __restrict__ force) {
    int k = blockIdx.x * blockDim.x + threadIdx.x;
    if (k < NNZ_) {
        float contrib = -vals[k] * dEflat[rows[k]];
        atomicAdd(&force[cols[k]], contrib);
    }
}

extern "C" void kernel_launch(void* const* d_in, const int* in_sizes, int n_in,
                              void* d_out, int out_size, void* d_ws, size_t ws_size,
                              hipStream_t stream) {
    (void)in_sizes; (void)n_in; (void)out_size;
    const float* fps  = (const float*)d_in[0];
    const float* W1   = (const float*)d_in[1];
    const float* b1   = (const float*)d_in[2];
    const float* W2   = (const float*)d_in[3];
    const float* b2   = (const float*)d_in[4];
    const float* W3   = (const float*)d_in[5];
    const float* b3   = (const float*)d_in[6];
    const int*   img  = (const int*)d_in[7];
    const int*   rows = (const int*)d_in[8];
    const int*   cols = (const int*)d_in[9];
    const float* vals = (const float*)d_in[10];

    char* ws = (char*)d_ws;
    // rank pipeline scratch (both paths)
    int*   g_hist  = (int*)(ws);                     //  5,068,800 B
    int*   g_total = (int*)(ws + 5068800);           //      7,200 B
    int*   g_base  = (int*)(ws + 5076000);           //      7,200 B
    int*   rank    = (int*)(ws + 5083200);           //    720,000 B
    float* dEflat  = (float*)(ws + 5803200);         // 28,800,000 B -> 34,603,200

    float* energy = (float*)d_out;                   // [1800]
    float* force  = (float*)d_out + NIMG_;           // [540000]

    const int nOut = NIMG_ + 3 * QTOT;
    zero_kernel<<<(nOut + BLK - 1) / BLK, BLK, 0, stream>>>((float*)d_out, nOut);

    // atom rank (stable argsort of image_idx)
    hist_kernel<<<NB, BLK, 0, stream>>>(img, g_hist);
    scan_blocks_kernel<<<NIMG_, BLK, 0, stream>>>(g_hist, g_total);
    scan_buckets_kernel<<<1, BLK, 0, stream>>>(g_total, g_base);
    rank_kernel<<<NB, BLK, 0, stream>>>(img, g_hist, g_base, rank);

    // per-atom MLP fwd+bwd
    dim3 gm((QE_ + BLK - 1) / BLK, E_);
    mlp_kernel<<<gm, BLK, 0, stream>>>(fps, W1, b1, W2, b2, W3, b3, img, rank,
                                       energy, dEflat);

    // v3 layout
    int*    binHist3  = (int*)(ws + 34603200);       //    957,264 B (132*1813*4)
    int*    binTotal3 = (int*)(ws + 35560464);       //        528 B
    int*    binBase3  = (int*)(ws + 35560992);       //      2,144 B
    int*    ctrl      = (int*)(ws + 35563136);       //     33,792 B
    uint32* itemX     = (uint32*)(ws + 35596928);    // 57,602,048 B
    uint32* itemY     = (uint32*)(ws + 93198976);    // 57,602,048 B
    uint32* bm3       = (uint32*)(ws + 150801024);   // 57,600,000 B -> 208,401,024
    float*  partial3  = (float*)(ws + 35596928);     // overlays itemX (dead by fforce)
    const size_t WS_V3 = 208401024;

    // R5 fallback layout
    int*    binHist5  = (int*)(ws + 34603200);       //    928,224 B (132*1758*4)
    int*    binTotal5 = (int*)(ws + 35531424);       //        528 B
    int*    binBase5  = (int*)(ws + 35531952);       //        544 B
    uint32* bm5       = (uint32*)(ws + 35532496);    // 57,600,000 B
    float*  partial5  = (float*)(ws + 93132496);     // 17,301,504 B
    const size_t WS_V2 = 110434000;

    if (ws_size >= WS_V3) {
        zero_ctrl_kernel<<<1, 256, 0, stream>>>(ctrl);
        slice_hist_kernel<<<NSB, BLK, 0, stream>>>(rows, ctrl);
        plan_kernel<<<1, BLK, 0, stream>>>(ctrl);
        slice_sort_kernel<<<NSB, BLK, 0, stream>>>(rows, cols, vals, ctrl, itemX, itemY);
        fhist3_kernel<<<MAXCH, BLK, 0, stream>>>(itemY, ctrl, binHist3);
        fscan_blocks_kernel<<<NBIN, BLK, 0, stream>>>(binHist3, binTotal3, MAXCH);
        fbase_kernel<<<1, BLK, 0, stream>>>(binTotal3, binBase3);
        fscatter3_kernel<<<FS_GRID, BLK, 0, stream>>>(itemX, itemY, dEflat, ctrl,
                                                      binHist3, binBase3, bm3);
        fforce_kernel<<<NBIN * SUBS, BLK, 0, stream>>>(bm3, binBase3, partial3);
        freduce_kernel<<<(3 * QTOT + BLK - 1) / BLK, BLK, 0, stream>>>(partial3, force);
    } else if (ws_size >= WS_V2) {
        fhist_kernel<<<NSB, BLK, 0, stream>>>(cols, binHist5);
        fscan_blocks_kernel<<<NBIN, BLK, 0, stream>>>(binHist5, binTotal5, NSB);
        fbase_kernel<<<1, BLK, 0, stream>>>(binTotal5, binBase5);
        fscatter_kernel<<<NSB, BLK, 0, stream>>>(rows, cols, vals, dEflat,
                                                 binHist5, binBase5, bm5);
        fforce_kernel<<<NBIN * SUBS, BLK, 0, stream>>>(bm5, binBase5, partial5);
        freduce_kernel<<<(3 * QTOT + BLK - 1) / BLK, BLK, 0, stream>>>(partial5, force);
    } else {
        force_kernel<<<NNZ_ / BLK, BLK, 0, stream>>>(rows, cols, vals, dEflat, force);
    }
}

// Round 7
// 604.405 us; speedup vs baseline: 1.1779x; 1.1779x over previous
//
#include <hip/hip_runtime.h>
#include <math.h>

#define E_    3
#define QE_   60000
#define QTOT  180000      // E_*QE_
#define P_    40
#define H_    20
#define NIMG_ 1800
#define NNZ_  14400000
#define BLK   256
#define NB    704         // ceil(QTOT/BLK)

// column-window partition for the sparse force accumulation
#define CW_BITS 12
#define CW      4096                  // cols per window (16 KB LDS accumulator)
#define NBIN    132                   // ceil(3*QTOT / CW)
#define SUBS    8                     // sub-slices per bin in force kernel
#define SC      8192                  // nnz items per chunk
#define NSB     1758                  // ceil(NNZ_/SC)  (input chunking)

// row-slice partition: 131072 dE rows = 512 KB per slice -> fits XCD L2
#define SLICE_SHIFT 17
#define NSLICE  55                    // ceil(7.2M / 131072)
#define CAPS    270336                // per-slice item capacity (33*SC, +16 sigma)
#define CAPB    114688                // per-bin bm capacity (+16 sigma)
#define MAXCH4  1815                  // 55*33 chunk slots
#define FS_GRID 768                   // fscatter4 blocks (3/CU)
#define FS_PERX 96                    // blocks per XCD group

// ctrl int offsets
#define C_SCUR  0      // [55]   slice cursors (= counts after slice_scatter)
#define C_BCUR  64     // [132]  bin cursors   (= counts after fscatter4)
#define C_GCNT  256    // [8]    per-XCD-group chunk counts
#define C_CHS   512    // [1815] chunk -> slice
#define C_CHST  2432   // [1815] chunk -> item start index
#define C_CHLEN 4352   // [1815] chunk -> length
#define C_GRP   6272   // [8*256] per-XCD-group chunk lists
#define C_INTS  8320

typedef int   vi4 __attribute__((ext_vector_type(4)));
typedef float vf4 __attribute__((ext_vector_type(4)));
typedef unsigned uint32;

// ---------------- zero init -------------------------------------------------
__global__ void zero_kernel(float* __restrict__ out, int n) {
    int i = blockIdx.x * blockDim.x + threadIdx.x;
    if (i < n) out[i] = 0.0f;
}
__global__ void zero_ctrl_kernel(int* __restrict__ ctrl) {
    ctrl[threadIdx.x] = 0;   // zeros C_SCUR + C_BCUR (first 256 ints)
}

// ---------------- stable counting sort for atom ranks ----------------------
__global__ void hist_kernel(const int* __restrict__ img, int* __restrict__ g_hist) {
    __shared__ int h[NIMG_];
    const int t = threadIdx.x, b = blockIdx.x;
    for (int v = t; v < NIMG_; v += BLK) h[v] = 0;
    __syncthreads();
    int a = b * BLK + t;
    if (a < QTOT) atomicAdd(&h[img[a]], 1);
    __syncthreads();
    for (int v = t; v < NIMG_; v += BLK) g_hist[v * NB + b] = h[v];
}

__global__ void scan_blocks_kernel(int* __restrict__ g_hist, int* __restrict__ g_total) {
    __shared__ int s[BLK];
    const int v = blockIdx.x, t = threadIdx.x;
    int carry = 0;
    for (int c = 0; c < NB; c += BLK) {
        int idx = c + t;
        int val = (idx < NB) ? g_hist[v * NB + idx] : 0;
        s[t] = val; __syncthreads();
        for (int off = 1; off < BLK; off <<= 1) {
            int tmp = (t >= off) ? s[t - off] : 0;
            __syncthreads();
            s[t] += tmp;
            __syncthreads();
        }
        int excl = s[t] - val;
        int tot  = s[BLK - 1];
        if (idx < NB) g_hist[v * NB + idx] = carry + excl;
        carry += tot;
        __syncthreads();
    }
    if (t == 0) g_total[v] = carry;
}

__global__ void scan_buckets_kernel(const int* __restrict__ g_total, int* __restrict__ g_base) {
    __shared__ int s[BLK];
    const int t = threadIdx.x;
    int carry = 0;
    for (int c = 0; c < NIMG_; c += BLK) {
        int idx = c + t;
        int val = (idx < NIMG_) ? g_total[idx] : 0;
        s[t] = val; __syncthreads();
        for (int off = 1; off < BLK; off <<= 1) {
            int tmp = (t >= off) ? s[t - off] : 0;
            __syncthreads();
            s[t] += tmp;
            __syncthreads();
        }
        if (idx < NIMG_) g_base[idx] = carry + (s[t] - val);
        carry += s[BLK - 1];
        __syncthreads();
    }
}

__global__ void rank_kernel(const int* __restrict__ img, const int* __restrict__ g_hist,
                            const int* __restrict__ g_base, int* __restrict__ rank) {
    __shared__ int simg[BLK];
    const int t = threadIdx.x, b = blockIdx.x;
    int a = b * BLK + t;
    int v = (a < QTOT) ? img[a] : -1;
    simg[t] = v;
    __syncthreads();
    if (a < QTOT) {
        int local = 0;
        for (int j = 0; j < t; ++j) {
            if (simg[j] == v) local++;
        }
        rank[a] = g_base[v] + g_hist[v * NB + b] + local;
    }
}

// ---------------- per-atom MLP forward + backward ---------------------------
__global__ __launch_bounds__(BLK) void mlp_kernel(
    const float* __restrict__ fps, const float* __restrict__ W1, const float* __restrict__ b1,
    const float* __restrict__ W2, const float* __restrict__ b2, const float* __restrict__ W3,
    const float* __restrict__ b3, const int* __restrict__ img, const int* __restrict__ rank,
    float* __restrict__ energy, float* __restrict__ dEflat)
{
    __shared__ float sW1[P_ * H_], sW2[H_ * H_], sW3[H_], sB1[H_], sB2[H_];
    __shared__ float sB3;
    const int e = blockIdx.y;
    const int t = threadIdx.x;
    for (int i = t; i < P_ * H_; i += BLK) sW1[i] = W1[e * P_ * H_ + i];
    for (int i = t; i < H_ * H_; i += BLK) sW2[i] = W2[e * H_ * H_ + i];
    if (t < H_) { sW3[t] = W3[e * H_ + t]; sB1[t] = b1[e * H_ + t]; sB2[t] = b2[e * H_ + t]; }
    if (t == 0) sB3 = b3[e];
    __syncthreads();

    int q = blockIdx.x * BLK + t;
    if (q >= QE_) return;
    int a = e * QE_ + q;

    const vf4* xp = (const vf4*)(fps + (size_t)a * P_);
    float x[P_];
    #pragma unroll
    for (int p = 0; p < P_; p += 4) {
        vf4 v4 = __builtin_nontemporal_load(xp + (p >> 2));
        x[p] = v4.x; x[p+1] = v4.y; x[p+2] = v4.z; x[p+3] = v4.w;
    }

    float h1v[H_], h2v[H_];
    #pragma unroll
    for (int i = 0; i < H_; ++i) {
        float z = sB1[i];
        #pragma unroll
        for (int p = 0; p < P_; ++p) z += x[p] * sW1[p * H_ + i];
        h1v[i] = tanhf(z);
    }
    #pragma unroll
    for (int i = 0; i < H_; ++i) {
        float z = sB2[i];
        #pragma unroll
        for (int j = 0; j < H_; ++j) z += h1v[j] * sW2[j * H_ + i];
        h2v[i] = tanhf(z);
    }
    float ea = sB3;
    #pragma unroll
    for (int i = 0; i < H_; ++i) ea += h2v[i] * sW3[i];
    atomicAdd(&energy[img[a]], ea);

    float dz2[H_];
    #pragma unroll
    for (int i = 0; i < H_; ++i) dz2[i] = sW3[i] * (1.0f - h2v[i] * h2v[i]);
    float dz1[H_];
    #pragma unroll
    for (int i = 0; i < H_; ++i) {
        float d = 0.0f;
        #pragma unroll
        for (int j = 0; j < H_; ++j) d += sW2[i * H_ + j] * dz2[j];
        dz1[i] = d * (1.0f - h1v[i] * h1v[i]);
    }
    float* op = dEflat + (size_t)rank[a] * P_;
    #pragma unroll
    for (int p = 0; p < P_; p += 4) {
        float4 v4;
        float d0 = 0.f, d1 = 0.f, d2 = 0.f, d3 = 0.f;
        #pragma unroll
        for (int i = 0; i < H_; ++i) {
            d0 += sW1[(p    ) * H_ + i] * dz1[i];
            d1 += sW1[(p + 1) * H_ + i] * dz1[i];
            d2 += sW1[(p + 2) * H_ + i] * dz1[i];
            d3 += sW1[(p + 3) * H_ + i] * dz1[i];
        }
        v4.x = d0; v4.y = d1; v4.z = d2; v4.w = d3;
        *(float4*)(op + p) = v4;   // cacheable: re-read by fscatter gather
    }
}

// ============ v4: capacity-reservation slice grouping + pinned gather =======

// slice_scatter: one streaming pass; group nnz by row-slice via per-block
// LDS hist + ONE global cursor atomicAdd per (block,slice). Runs ~1.2 KB.
// item = { (val15<<17)|rowLocal17 , col }
__global__ __launch_bounds__(BLK) void slice_scatter_kernel(
    const int* __restrict__ rows, const int* __restrict__ cols, const float* __restrict__ vals,
    int* __restrict__ ctrl, uint2* __restrict__ items)
{
    __shared__ uint32 srow[SC];          // 32 KB staged rows
    __shared__ int h[NSLICE], lcur[NSLICE], gbase[NSLICE];
    const int t = threadIdx.x, b = blockIdx.x;
    const int base = b * SC;
    const int len = min(SC, NNZ_ - base);
    const bool full = (len == SC);

    if (t < NSLICE) h[t] = 0;
    __syncthreads();
    if (full) {
        const vi4* r4 = (const vi4*)(rows + base);
        #pragma unroll
        for (int j = 0; j < SC / (BLK * 4); ++j) {
            int idx = j * BLK + t;
            vi4 rr = __builtin_nontemporal_load(r4 + idx);
            srow[idx * 4 + 0] = (uint32)rr.x; atomicAdd(&h[rr.x >> SLICE_SHIFT], 1);
            srow[idx * 4 + 1] = (uint32)rr.y; atomicAdd(&h[rr.y >> SLICE_SHIFT], 1);
            srow[idx * 4 + 2] = (uint32)rr.z; atomicAdd(&h[rr.z >> SLICE_SHIFT], 1);
            srow[idx * 4 + 3] = (uint32)rr.w; atomicAdd(&h[rr.w >> SLICE_SHIFT], 1);
        }
    } else {
        for (int j = t; j < len; j += BLK) {
            int r = rows[base + j];
            srow[j] = (uint32)r;
            atomicAdd(&h[r >> SLICE_SHIFT], 1);
        }
    }
    __syncthreads();
    if (t < NSLICE) {
        lcur[t] = 0;
        gbase[t] = (h[t] > 0) ? atomicAdd(&ctrl[C_SCUR + t], h[t]) : 0;
    }
    __syncthreads();
    if (full) {
        const vi4* c4 = (const vi4*)(cols + base);
        const vi4* v4 = (const vf4*)(vals + base) ? (const vi4*)(vals + base) : nullptr;
        #pragma unroll 2
        for (int j = 0; j < SC / (BLK * 4); ++j) {
            int idx = j * BLK + t;
            vi4 cc = __builtin_nontemporal_load(c4 + idx);
            vi4 vv = __builtin_nontemporal_load(v4 + idx);
            #define EMIT(K, CI, VB)                                                \
            {                                                                      \
                uint32 r = srow[idx * 4 + K];                                      \
                int sl = (int)(r >> SLICE_SHIFT);                                  \
                int pos = gbase[sl] + atomicAdd(&lcur[sl], 1);                     \
                uint32 v15 = (((uint32)(VB)) + 0x10000u) >> 17;                    \
                items[(size_t)sl * CAPS + pos] =                                   \
                    make_uint2((v15 << 17) | (r & 0x1FFFFu), (uint32)(CI));        \
            }
            EMIT(0, cc.x, vv.x)
            EMIT(1, cc.y, vv.y)
            EMIT(2, cc.z, vv.z)
            EMIT(3, cc.w, vv.w)
        }
    } else {
        for (int j = t; j < len; j += BLK) {
            uint32 r = srow[j];
            int sl = (int)(r >> SLICE_SHIFT);
            int pos = gbase[sl] + atomicAdd(&lcur[sl], 1);
            uint32 vb = ((const uint32*)vals)[base + j];
            uint32 v15 = (vb + 0x10000u) >> 17;
            items[(size_t)sl * CAPS + pos] =
                make_uint2((v15 << 17) | (r & 0x1FFFFu), (uint32)cols[base + j]);
        }
    }
}

// plan4: slice counts -> chunk tables + XCD group lists.
__global__ void plan4_kernel(int* __restrict__ ctrl) {
    __shared__ int scnt[NSLICE], cb[NSLICE + 1], gp[NSLICE];
    __shared__ int g8[8], tot_s;
    const int t = threadIdx.x;
    if (t < NSLICE) scnt[t] = ctrl[C_SCUR + t];
    __syncthreads();
    if (t == 0) {
        int crun = 0;
        int gs[8]; for (int x = 0; x < 8; ++x) gs[x] = 0;
        for (int s = 0; s < NSLICE; ++s) {
            int nc = (scnt[s] + SC - 1) / SC;
            cb[s] = crun; crun += nc;
            int x = s & 7;
            gp[s] = gs[x]; gs[x] += nc;
        }
        cb[NSLICE] = crun; tot_s = crun;
        for (int x = 0; x < 8; ++x) g8[x] = gs[x];
    }
    __syncthreads();
    const int tot = tot_s;
    if (t < 8) ctrl[C_GCNT + t] = g8[t];
    for (int idx = t; idx < tot; idx += BLK) {
        int s = 0;
        for (int k = 0; k < NSLICE; ++k) if (cb[k] <= idx) s = k;
        int c = idx - cb[s];
        ctrl[C_CHS + idx]   = s;
        ctrl[C_CHST + idx]  = s * CAPS + c * SC;
        ctrl[C_CHLEN + idx] = min(SC, scnt[s] - c * SC);
        ctrl[C_GRP + (s & 7) * 256 + gp[s] + c] = idx;
    }
}

// fscatter4: XCD-pinned chunks; L2-local gather, fused multiply, block-local
// col sort, capacity-reserved coalesced write-out. No histogram prepass kernels.
__global__ __launch_bounds__(BLK) void fscatter4_kernel(
    const uint2* __restrict__ items, const float* __restrict__ dEflat,
    int* __restrict__ ctrl, uint32* __restrict__ bm)
{
    __shared__ uint32 itl[SC];            // 32 KB
    __shared__ unsigned char bns[SC];     //  8 KB
    __shared__ int h[NBIN], cur[NBIN], dlt[NBIN];
    __shared__ int sc[BLK];
    const int t = threadIdx.x;
    const int x = blockIdx.x & 7;         // assumed XCD (round-robin dispatch)
    const int r = blockIdx.x >> 3;
    const int gc = ctrl[C_GCNT + x];

    for (int w = r; w < gc; w += FS_PERX) {
        const int g     = ctrl[C_GRP + x * 256 + w];
        const int sl    = ctrl[C_CHS + g];
        const int start = ctrl[C_CHST + g];
        const int len   = ctrl[C_CHLEN + g];
        const int row0  = sl << SLICE_SHIFT;
        const int lenE  = len & ~1;

        if (t < NBIN) h[t] = 0;
        __syncthreads();
        // pass 1: histogram over cols (items.y)
        if (len == SC) {
            const vi4* p4 = (const vi4*)(items + start);
            #pragma unroll
            for (int j = 0; j < SC / (BLK * 2); ++j) {
                vi4 q = __builtin_nontemporal_load(p4 + j * BLK + t);
                atomicAdd(&h[((uint32)q.y) >> CW_BITS], 1);
                atomicAdd(&h[((uint32)q.w) >> CW_BITS], 1);
            }
        } else {
            for (int j = t; j < len; j += BLK)
                atomicAdd(&h[items[start + j].y >> CW_BITS], 1);
        }
        __syncthreads();
        // local scan -> cur; global capacity reservation -> dlt
        {
            int v = (t < NBIN) ? h[t] : 0;
            sc[t] = v; __syncthreads();
            for (int off = 1; off < BLK; off <<= 1) {
                int tmp = (t >= off) ? sc[t - off] : 0;
                __syncthreads();
                sc[t] += tmp;
                __syncthreads();
            }
            if (t < NBIN) {
                int ls = sc[t] - v;
                cur[t] = ls;
                int gb = (v > 0) ? atomicAdd(&ctrl[C_BCUR + t], v) : 0;
                dlt[t] = t * CAPB + gb - ls;
            }
        }
        __syncthreads();
        // pass 2: gather (L2-local) + fused multiply + local placement
        #define PLACE4(LO, CO, DI)                                             \
        {                                                                      \
            uint32 col = (uint32)(CO);                                         \
            int bin = (int)(col >> CW_BITS);                                   \
            float val = __uint_as_float((((uint32)(LO)) >> 17) << 17);         \
            uint32 u = __float_as_uint(-val * (DI));                           \
            uint32 pk = ((col & (CW - 1)) << 20) | ((u + 0x800u) >> 12);       \
            int pos = atomicAdd(&cur[bin], 1);                                 \
            itl[pos] = pk;                                                     \
            bns[pos] = (unsigned char)bin;                                     \
        }
        if (len == SC) {
            const vi4* p4 = (const vi4*)(items + start);
            #pragma unroll 2
            for (int j = 0; j < SC / (BLK * 2); ++j) {
                vi4 q = __builtin_nontemporal_load(p4 + j * BLK + t);
                float dA = dEflat[row0 + (((uint32)q.x) & 0x1FFFFu)];
                float dB = dEflat[row0 + (((uint32)q.z) & 0x1FFFFu)];
                PLACE4(q.x, q.y, dA)
                PLACE4(q.z, q.w, dB)
            }
        } else {
            for (int j = t; j < len; j += BLK) {
                uint2 it = items[start + j];
                float d = dEflat[row0 + (it.x & 0x1FFFFu)];
                PLACE4(it.x, it.y, d)
            }
        }
        __syncthreads();
        // coalesced write-out in sorted order
        for (int i = t; i < len; i += BLK) {
            __builtin_nontemporal_store(itl[i], &bm[dlt[bns[i]] + i]);
        }
        __syncthreads();
    }
}

// fforce4: per (bin, sub-slice) LDS accumulation over capacity-based bm.
__global__ __launch_bounds__(BLK) void fforce4_kernel(
    const uint32* __restrict__ bm, const int* __restrict__ ctrl,
    float* __restrict__ partial)
{
    __shared__ float w[CW];
    const int t = threadIdx.x;
    const int bin = blockIdx.x >> 3;
    const int sub = blockIdx.x & (SUBS - 1);
    for (int i = t; i < CW; i += BLK) w[i] = 0.0f;
    __syncthreads();
    const int cnt   = ctrl[C_BCUR + bin];
    const int start = bin * CAPB;
    const int sBeg  = start + (cnt * sub) / SUBS;
    const int sEnd  = start + (cnt * (sub + 1)) / SUBS;
    int i = sBeg + t;
    for (; i + 3 * BLK < sEnd; i += 4 * BLK) {
        uint32 p0 = __builtin_nontemporal_load(bm + i);
        uint32 p1 = __builtin_nontemporal_load(bm + i + BLK);
        uint32 p2 = __builtin_nontemporal_load(bm + i + 2 * BLK);
        uint32 p3 = __builtin_nontemporal_load(bm + i + 3 * BLK);
        atomicAdd(&w[p0 >> 20], __uint_as_float((p0 & 0xFFFFFu) << 12));
        atomicAdd(&w[p1 >> 20], __uint_as_float((p1 & 0xFFFFFu) << 12));
        atomicAdd(&w[p2 >> 20], __uint_as_float((p2 & 0xFFFFFu) << 12));
        atomicAdd(&w[p3 >> 20], __uint_as_float((p3 & 0xFFFFFu) << 12));
    }
    for (; i < sEnd; i += BLK) {
        uint32 p = bm[i];
        atomicAdd(&w[p >> 20], __uint_as_float((p & 0xFFFFFu) << 12));
    }
    __syncthreads();
    float* dst = partial + (size_t)blockIdx.x * CW;
    for (int k = t; k < CW; k += BLK) __builtin_nontemporal_store(w[k], dst + k);
}

__global__ void freduce_kernel(const float* __restrict__ partial, float* __restrict__ force) {
    int i = blockIdx.x * BLK + threadIdx.x;
    if (i < 3 * QTOT) {
        int bin = i >> CW_BITS, local = i & (CW - 1);
        const float* p = partial + (size_t)bin * (CW * SUBS) + local;
        float sum = 0.0f;
        #pragma unroll
        for (int k = 0; k < SUBS; ++k) sum += __builtin_nontemporal_load(p + k * CW);
        force[i] = sum;
    }
}

// ================= R5 fallback path (unsliced) ==============================
__global__ __launch_bounds__(BLK) void fhist_kernel(const int* __restrict__ cols,
                                                    int* __restrict__ binHist) {
    __shared__ int h[NBIN];
    const int t = threadIdx.x, b = blockIdx.x;
    if (t < NBIN) h[t] = 0;
    __syncthreads();
    const int base = b * SC;
    if (base + SC <= NNZ_) {
        const vi4* c4 = (const vi4*)(cols + base);
        #pragma unroll
        for (int j = 0; j < SC / (BLK * 4); ++j) {
            vi4 cc = __builtin_nontemporal_load(c4 + j * BLK + t);
            atomicAdd(&h[cc.x >> CW_BITS], 1);
            atomicAdd(&h[cc.y >> CW_BITS], 1);
            atomicAdd(&h[cc.z >> CW_BITS], 1);
            atomicAdd(&h[cc.w >> CW_BITS], 1);
        }
    } else {
        for (int j = 0; j < SC / BLK; ++j) {
            int k = base + j * BLK + t;
            if (k < NNZ_) atomicAdd(&h[cols[k] >> CW_BITS], 1);
        }
    }
    __syncthreads();
    if (t < NBIN) binHist[t * NSB + b] = h[t];
}

__global__ void fscan_blocks_kernel(int* __restrict__ binHist, int* __restrict__ binTotal,
                                    int n) {
    __shared__ int s[BLK];
    const int v = blockIdx.x, t = threadIdx.x;
    int carry = 0;
    for (int c = 0; c < n; c += BLK) {
        int idx = c + t;
        int val = (idx < n) ? binHist[v * n + idx] : 0;
        s[t] = val; __syncthreads();
        for (int off = 1; off < BLK; off <<= 1) {
            int tmp = (t >= off) ? s[t - off] : 0;
            __syncthreads();
            s[t] += tmp;
            __syncthreads();
        }
        int excl = s[t] - val;
        int tot  = s[BLK - 1];
        if (idx < n) binHist[v * n + idx] = carry + excl;
        carry += tot;
        __syncthreads();
    }
    if (t == 0) binTotal[v] = carry;
}

__global__ void fbase_kernel(const int* __restrict__ binTotal, int* __restrict__ binBase) {
    __shared__ int s[BLK];
    const int t = threadIdx.x;
    int v = (t < NBIN) ? binTotal[t] : 0;
    s[t] = v; __syncthreads();
    for (int off = 1; off < BLK; off <<= 1) {
        int tmp = (t >= off) ? s[t - off] : 0;
        __syncthreads();
        s[t] += tmp;
        __syncthreads();
    }
    if (t < NBIN) binBase[t] = s[t] - v;
    if (t == 0) binBase[NBIN] = s[BLK - 1];
}

__global__ __launch_bounds__(BLK) void fscatter_kernel(
    const int* __restrict__ rows, const int* __restrict__ cols, const float* __restrict__ vals,
    const float* __restrict__ dEflat, const int* __restrict__ binHist,
    const int* __restrict__ binBase, uint32* __restrict__ bm)
{
    __shared__ uint32 items[SC];
    __shared__ unsigned char bins[SC];
    __shared__ int hist[NBIN];
    __shared__ int cursor[NBIN];
    __shared__ int delta[NBIN];
    __shared__ int s[BLK];
    const int t = threadIdx.x, b = blockIdx.x;
    const int base = b * SC;
    const int nIt = min(SC, NNZ_ - base);
    const bool full = (base + SC <= NNZ_);

    if (t < NBIN) hist[t] = 0;
    __syncthreads();
    if (full) {
        const vi4* c4 = (const vi4*)(cols + base);
        #pragma unroll
        for (int j = 0; j < SC / (BLK * 4); ++j) {
            vi4 cc = __builtin_nontemporal_load(c4 + j * BLK + t);
            atomicAdd(&hist[cc.x >> CW_BITS], 1);
            atomicAdd(&hist[cc.y >> CW_BITS], 1);
            atomicAdd(&hist[cc.z >> CW_BITS], 1);
            atomicAdd(&hist[cc.w >> CW_BITS], 1);
        }
    } else {
        for (int j = 0; j < SC / BLK; ++j) {
            int k = base + j * BLK + t;
            if (k < NNZ_) atomicAdd(&hist[cols[k] >> CW_BITS], 1);
        }
    }
    __syncthreads();
    {
        int v = (t < NBIN) ? hist[t] : 0;
        s[t] = v; __syncthreads();
        for (int off = 1; off < BLK; off <<= 1) {
            int tmp = (t >= off) ? s[t - off] : 0;
            __syncthreads();
            s[t] += tmp;
            __syncthreads();
        }
        if (t < NBIN) {
            int ls = s[t] - v;
            cursor[t] = ls;
            delta[t]  = binBase[t] + binHist[t * NSB + b] - ls;
        }
    }
    __syncthreads();
    if (full) {
        const vi4* c4 = (const vi4*)(cols + base);
        const vi4* r4 = (const vi4*)(rows + base);
        const vf4* v4 = (const vf4*)(vals + base);
        #pragma unroll 2
        for (int j = 0; j < SC / (BLK * 4); ++j) {
            int idx = j * BLK + t;
            vi4 cc = __builtin_nontemporal_load(c4 + idx);
            vi4 rr = __builtin_nontemporal_load(r4 + idx);
            vf4 vv = __builtin_nontemporal_load(v4 + idx);
            float d0 = dEflat[rr.x];
            float d1 = dEflat[rr.y];
            float d2 = dEflat[rr.z];
            float d3 = dEflat[rr.w];
            #define PLACE(CI, VI, DI)                                              \
            {                                                                      \
                int bin = (CI) >> CW_BITS;                                         \
                uint32 u = __float_as_uint(-(VI) * (DI));                          \
                uint32 pk = ((uint32)((CI) & (CW - 1)) << 20)                      \
                            | ((u + 0x800u) >> 12);                                \
                int pos = atomicAdd(&cursor[bin], 1);                              \
                items[pos] = pk;                                                   \
                bins[pos] = (unsigned char)bin;                                    \
            }
            PLACE(cc.x, vv.x, d0)
            PLACE(cc.y, vv.y, d1)
            PLACE(cc.z, vv.z, d2)
            PLACE(cc.w, vv.w, d3)
        }
    } else {
        for (int j = 0; j < SC / BLK; ++j) {
            int k = base + j * BLK + t;
            if (k < NNZ_) {
                int c = cols[k];
                float d = dEflat[rows[k]];
                float v = vals[k];
                PLACE(c, v, d)
            }
        }
    }
    __syncthreads();
    for (int i = t; i < nIt; i += BLK) {
        __builtin_nontemporal_store(items[i], &bm[delta[bins[i]] + i]);
    }
}

__global__ __launch_bounds__(BLK) void fforce_kernel(
    const uint32* __restrict__ bm, const int* __restrict__ binBase,
    float* __restrict__ partial)
{
    __shared__ float w[CW];
    const int t = threadIdx.x;
    const int bin = blockIdx.x >> 3;
    const int sub = blockIdx.x & (SUBS - 1);
    for (int i = t; i < CW; i += BLK) w[i] = 0.0f;
    __syncthreads();
    const int start = binBase[bin];
    const int cnt   = binBase[bin + 1] - start;
    const int sBeg  = start + (cnt * sub) / SUBS;
    const int sEnd  = start + (cnt * (sub + 1)) / SUBS;
    int i = sBeg + t;
    for (; i + 3 * BLK < sEnd; i += 4 * BLK) {
        uint32 p0 = __builtin_nontemporal_load(bm + i);
        uint32 p1 = __builtin_nontemporal_load(bm + i + BLK);
        uint32 p2 = __builtin_nontemporal_load(bm + i + 2 * BLK);
        uint32 p3 = __builtin_nontemporal_load(bm + i + 3 * BLK);
        atomicAdd(&w[p0 >> 20], __uint_as_float((p0 & 0xFFFFFu) << 12));
        atomicAdd(&w[p1 >> 20], __uint_as_float((p1 & 0xFFFFFu) << 12));
        atomicAdd(&w[p2 >> 20], __uint_as_float((p2 & 0xFFFFFu) << 12));
        atomicAdd(&w[p3 >> 20], __uint_as_float((p3 & 0xFFFFFu) << 12));
    }
    for (; i < sEnd; i += BLK) {
        uint32 p = bm[i];
        atomicAdd(&w[p >> 20], __uint_as_float((p & 0xFFFFFu) << 12));
    }
    __syncthreads();
    float* dst = partial + (size_t)blockIdx.x * CW;
    for (int k = t; k < CW; k += BLK) __builtin_nontemporal_store(w[k], dst + k);
}

__global__ void force_kernel(const int* __restrict__ rows, const int* __restrict__ cols,
                             const float* __restrict__ vals, const float* __restrict__ dEflat,
                             float* __restrict__ force) {
    int k = blockIdx.x * blockDim.x + threadIdx.x;
    if (k < NNZ_) {
        float contrib = -vals[k] * dEflat[rows[k]];
        atomicAdd(&force[cols[k]], contrib);
    }
}

extern "C" void kernel_launch(void* const* d_in, const int* in_sizes, int n_in,
                              void* d_out, int out_size, void* d_ws, size_t ws_size,
                              hipStream_t stream) {
    (void)in_sizes; (void)n_in; (void)out_size;
    const float* fps  = (const float*)d_in[0];
    const float* W1   = (const float*)d_in[1];
    const float* b1   = (const float*)d_in[2];
    const float* W2   = (const float*)d_in[3];
    const float* b2   = (const float*)d_in[4];
    const float* W3   = (const float*)d_in[5];
    const float* b3   = (const float*)d_in[6];
    const int*   img  = (const int*)d_in[7];
    const int*   rows = (const int*)d_in[8];
    const int*   cols = (const int*)d_in[9];
    const float* vals = (const float*)d_in[10];

    char* ws = (char*)d_ws;
    float* energy = (float*)d_out;                   // [1800]
    float* force  = (float*)d_out + NIMG_;           // [540000]
    const int nOut = NIMG_ + 3 * QTOT;

    // v4 layout (fits known 208.4 MB floor):
    //   [0, 5.80 MB)      rank scratch  (dead after mlp)
    //   [0, 118.95 MB)    items uint2[55*CAPS]     (overlay; live after mlp)
    //   [0, 17.30 MB)     partial (overlay items; live after fscatter4)
    //   [118.95, 179.50)  bm uint32[132*CAPB]
    //   [179.50, 179.54)  ctrl
    //   [179.54, 208.34)  dEflat
    int*    g_hist  = (int*)(ws);
    int*    g_total = (int*)(ws + 5068800);
    int*    g_base  = (int*)(ws + 5076000);
    int*    rank    = (int*)(ws + 5083200);
    uint2*  items   = (uint2*)(ws);
    float*  partial4= (float*)(ws);
    uint32* bm4     = (uint32*)(ws + 118947840);
    int*    ctrl    = (int*)(ws + 179503104);
    float*  dEflat4 = (float*)(ws + 179536384);
    const size_t WS_V4 = 208336384;

    // R5 fallback layout
    float*  dEflat5   = (float*)(ws + 5803200);
    int*    binHist5  = (int*)(ws + 34603200);
    int*    binTotal5 = (int*)(ws + 35531424);
    int*    binBase5  = (int*)(ws + 35531952);
    uint32* bm5       = (uint32*)(ws + 35532496);
    float*  partial5  = (float*)(ws + 93132496);
    const size_t WS_V2 = 110434000;

    const bool v4 = (ws_size >= WS_V4);
    float* dEflat = v4 ? dEflat4 : dEflat5;

    zero_kernel<<<(nOut + BLK - 1) / BLK, BLK, 0, stream>>>((float*)d_out, nOut);

    // atom rank (stable argsort of image_idx)
    hist_kernel<<<NB, BLK, 0, stream>>>(img, g_hist);
    scan_blocks_kernel<<<NIMG_, BLK, 0, stream>>>(g_hist, g_total);
    scan_buckets_kernel<<<1, BLK, 0, stream>>>(g_total, g_base);
    rank_kernel<<<NB, BLK, 0, stream>>>(img, g_hist, g_base, rank);

    // per-atom MLP fwd+bwd
    dim3 gm((QE_ + BLK - 1) / BLK, E_);
    mlp_kernel<<<gm, BLK, 0, stream>>>(fps, W1, b1, W2, b2, W3, b3, img, rank,
                                       energy, dEflat);

    if (v4) {
        zero_ctrl_kernel<<<1, 256, 0, stream>>>(ctrl);
        slice_scatter_kernel<<<NSB, BLK, 0, stream>>>(rows, cols, vals, ctrl, items);
        plan4_kernel<<<1, BLK, 0, stream>>>(ctrl);
        fscatter4_kernel<<<FS_GRID, BLK, 0, stream>>>(items, dEflat, ctrl, bm4);
        fforce4_kernel<<<NBIN * SUBS, BLK, 0, stream>>>(bm4, ctrl, partial4);
        freduce_kernel<<<(3 * QTOT + BLK - 1) / BLK, BLK, 0, stream>>>(partial4, force);
    } else if (ws_size >= WS_V2) {
        fhist_kernel<<<NSB, BLK, 0, stream>>>(cols, binHist5);
        fscan_blocks_kernel<<<NBIN, BLK, 0, stream>>>(binHist5, binTotal5, NSB);
        fbase_kernel<<<1, BLK, 0, stream>>>(binTotal5, binBase5);
        fscatter_kernel<<<NSB, BLK, 0, stream>>>(rows, cols, vals, dEflat,
                                                 binHist5, binBase5, bm5);
        fforce_kernel<<<NBIN * SUBS, BLK, 0, stream>>>(bm5, binBase5, partial5);
        freduce_kernel<<<(3 * QTOT + BLK - 1) / BLK, BLK, 0, stream>>>(partial5, force);
    } else {
        force_kernel<<<NNZ_ / BLK, BLK, 0, stream>>>(rows, cols, vals, dEflat, force);
    }
}